// Round 11
// baseline (247.970 us; speedup 1.0000x reference)
//
#include <hip/hip_runtime.h>
#include <hip/hip_bf16.h>

typedef __bf16 bf16x8 __attribute__((ext_vector_type(8)));
typedef float f32x4 __attribute__((ext_vector_type(4)));

static __device__ __forceinline__ __bf16 tobf(float x) {
    __hip_bfloat16 h = __float2bfloat16(x);
    __bf16 r;
    __builtin_memcpy(&r, &h, 2);
    return r;
}

// fast 2^x: single v_exp_f32 (no libm range-fixup code)
static __device__ __forceinline__ float fexp2(float x) {
    float r;
    asm("v_exp_f32 %0, %1" : "=v"(r) : "v"(x));
    return r;
}

// ---------------------------------------------------------------------------
// Fused prep: (a) x fp32 -> bf16 (vectorized), (b) W_attn^T with qscale
// folded into Q columns, (c) W_proj^T.  One launch instead of three.
// ---------------------------------------------------------------------------
__global__ __launch_bounds__(256) void prep_k(const float* __restrict__ x,
                                              __hip_bfloat16* __restrict__ x_bf,
                                              const float* __restrict__ Wa,
                                              __hip_bfloat16* __restrict__ WaT,
                                              const float* __restrict__ Wp,
                                              __hip_bfloat16* __restrict__ WpT) {
    __shared__ float tile[32][33];
    const int bid = blockIdx.x;
    const int tid = threadIdx.x;
    if (bid < 8192) {
        int i = bid * 256 + tid;
        float4 v = reinterpret_cast<const float4*>(x)[i];
        __hip_bfloat16 a = __float2bfloat16(v.x);
        __hip_bfloat16 b = __float2bfloat16(v.y);
        __hip_bfloat16 c = __float2bfloat16(v.z);
        __hip_bfloat16 d = __float2bfloat16(v.w);
        ushort4 o;
        o.x = *reinterpret_cast<unsigned short*>(&a);
        o.y = *reinterpret_cast<unsigned short*>(&b);
        o.z = *reinterpret_cast<unsigned short*>(&c);
        o.w = *reinterpret_cast<unsigned short*>(&d);
        reinterpret_cast<ushort4*>(x_bf)[i] = o;
        return;
    }
    const float* in;
    __hip_bfloat16* out;
    int bx, Cn, qrows;
    float qscale;
    int t;
    if (bid < 8192 + 3072) {
        t = bid - 8192;
        in = Wa; out = WaT; Cn = 3072; qrows = 1024;
        qscale = 0.045084223f;  // log2(e)/sqrt(1024)
        bx = t % 96;
    } else {
        t = bid - 11264;
        in = Wp; out = WpT; Cn = 1024; qrows = 0;
        qscale = 1.0f;
        bx = t % 32;
    }
    const int by = (bid < 11264) ? (t / 96) : (t / 32);
    const int R = 1024;
    const int c0 = bx * 32, r0 = by * 32;
    const int tx = tid & 31, ty = tid >> 5;  // 32 x 8
#pragma unroll
    for (int i = 0; i < 4; ++i)
        tile[ty + i * 8][tx] = in[(size_t)(r0 + ty + i * 8) * Cn + c0 + tx];
    __syncthreads();
#pragma unroll
    for (int i = 0; i < 4; ++i) {
        int orow = c0 + ty + i * 8;
        float v = tile[tx][ty + i * 8];
        if (orow < qrows) v *= qscale;
        out[(size_t)orow * R + r0 + tx] = __float2bfloat16(v);
    }
}

// ---------------------------------------------------------------------------
// V transpose + key-permute: qkv V-section [b][t][h*64+d] ->
// Vt[(b*16+h)*64+d][slot(t)], slot(r) = ((r&12)<<1)|(r&3)|((r>>4)<<2) within
// each 32-key block. Matches the register layout of swapped-QK^T P frags so
// the PV A-operand is a pure register pack.
// ---------------------------------------------------------------------------
__global__ __launch_bounds__(256) void vtrans_k(const __hip_bfloat16* __restrict__ qkv,
                                                __hip_bfloat16* __restrict__ Vt) {
    __shared__ __hip_bfloat16 tile[32][33];
    const int bh = blockIdx.z, b = bh >> 4, h = bh & 15;
    const int tt = blockIdx.x;  // 0..63 (t tile)
    const int dt = blockIdx.y;  // 0..1  (d tile)
    const int tx = threadIdx.x & 31, ty = threadIdx.x >> 5;  // 32 x 8
    const __hip_bfloat16* src = qkv + (size_t)b * 2048 * 3072 + 2048 + h * 64;
#pragma unroll
    for (int i = 0; i < 4; ++i)
        tile[ty + i * 8][tx] = src[(size_t)(tt * 32 + ty + i * 8) * 3072 + dt * 32 + tx];
    __syncthreads();
    const int slot = ((tx & 12) << 1) | (tx & 3) | ((tx >> 4) << 2);
    __hip_bfloat16* dst = Vt + ((size_t)bh * 64 + dt * 32) * 2048 + tt * 32;
#pragma unroll
    for (int i = 0; i < 4; ++i)
        dst[(size_t)(ty + i * 8) * 2048 + slot] = tile[tx][ty + i * 8];
}

// ---------------------------------------------------------------------------
// bf16 GEMM, C = A[M][K] * B, with B given transposed: Bt[N][K].
// m97 structure: 128x128 tile, BK=32, 4 waves each owning 64x64.
// XCD-aware tile swizzle (grid size must be divisible by 8 -> true here).
// ---------------------------------------------------------------------------
template <bool OUT_BF16>
__global__ __launch_bounds__(256) void gemm_bt(const __hip_bfloat16* __restrict__ A,
                                               const __hip_bfloat16* __restrict__ Bt,
                                               __hip_bfloat16* __restrict__ Cb,
                                               float* __restrict__ Cf,
                                               int M, int N, int K) {
    __shared__ __attribute__((aligned(16))) __hip_bfloat16 As[128 * 32];
    __shared__ __attribute__((aligned(16))) __hip_bfloat16 Bs[128 * 32];
    const int tid = threadIdx.x;
    const int lane = tid & 63, wid = tid >> 6;
    const int l15 = lane & 15, lg = lane >> 4;
    const int wr = wid >> 1, wc = wid & 1;
    // XCD swizzle: each XCD gets a contiguous chunk of tile-space
    const int lin = blockIdx.y * gridDim.x + blockIdx.x;
    const int cpx = (gridDim.x * gridDim.y) >> 3;
    const int sw = (lin & 7) * cpx + (lin >> 3);
    const int bn = sw % gridDim.x, bm = sw / gridDim.x;
    const size_t arow0 = (size_t)bm * 128;
    const size_t brow0 = (size_t)bn * 128;

    f32x4 acc[4][4] = {};

    const int nk = K >> 5;
    for (int kt = 0; kt < nk; ++kt) {
        __syncthreads();
        {
            const int k0 = kt * 32;
#pragma unroll
            for (int p = 0; p < 2; ++p) {
                int idx = p * 256 + tid;
                int row = idx >> 2;
                int cc = (idx & 3) * 8;
                const __hip_bfloat16* ga = A + (arow0 + row) * (size_t)K + k0 + cc;
                const __hip_bfloat16* gb = Bt + (brow0 + row) * (size_t)K + k0 + cc;
                __builtin_amdgcn_global_load_lds(
                    (const __attribute__((address_space(1))) void*)ga,
                    (__attribute__((address_space(3))) void*)(&As[idx * 8]), 16, 0, 0);
                __builtin_amdgcn_global_load_lds(
                    (const __attribute__((address_space(1))) void*)gb,
                    (__attribute__((address_space(3))) void*)(&Bs[idx * 8]), 16, 0, 0);
            }
        }
        __syncthreads();
        bf16x8 af[4], bfr[4];
#pragma unroll
        for (int m = 0; m < 4; ++m)
            af[m] = *reinterpret_cast<const bf16x8*>(&As[(wr * 64 + m * 16 + l15) * 32 + lg * 8]);
#pragma unroll
        for (int n = 0; n < 4; ++n)
            bfr[n] = *reinterpret_cast<const bf16x8*>(&Bs[(wc * 64 + n * 16 + l15) * 32 + lg * 8]);
#pragma unroll
        for (int m = 0; m < 4; ++m)
#pragma unroll
            for (int n = 0; n < 4; ++n)
                acc[m][n] = __builtin_amdgcn_mfma_f32_16x16x32_bf16(af[m], bfr[n], acc[m][n], 0, 0, 0);
    }

#pragma unroll
    for (int m = 0; m < 4; ++m) {
#pragma unroll
        for (int n = 0; n < 4; ++n) {
#pragma unroll
            for (int j = 0; j < 4; ++j) {
                int row = bm * 128 + wr * 64 + m * 16 + lg * 4 + j;
                int col = bn * 128 + wc * 64 + n * 16 + l15;
                if (OUT_BF16)
                    Cb[(size_t)row * N + col] = __float2bfloat16(acc[m][n][j]);
                else
                    Cf[(size_t)row * N + col] = acc[m][n][j];
            }
        }
    }
}

// ---------------------------------------------------------------------------
// Flash attention (causal): barrier-free 1-wave blocks.
// Each 64-thread block = 1 wave handling 32 q-rows of one (bh, qt, half);
// grid (bh=64, yb=64), qt = 31 - (yb>>1) heavy-first -> backfill balances.
// No LDS, no barriers: K fragments load direct from qkv (rows are whole
// 128B L2 lines; same-bh blocks land on one XCD -> K/V L2-resident),
// V direct from key-permuted Vt. Max-free softmax (scores pre-scaled by
// log2e/sqrt(C) via W_attn): p = 2^s via single v_exp_f32; row sums
// accumulate in-lane, cross-lane reduce once in the epilogue.
// ---------------------------------------------------------------------------
__global__ __launch_bounds__(64, 3) void attn_k(const __hip_bfloat16* __restrict__ qkv,
                                                const __hip_bfloat16* __restrict__ Vt,
                                                __hip_bfloat16* __restrict__ y) {
    constexpr int TT = 2048;
    constexpr int S3C = 3072;
    const int bh = blockIdx.x, b = bh >> 4, h = bh & 15;
    const int yb = blockIdx.y;
    const int qt = 31 - (yb >> 1);  // heavy first
    const int w = yb & 1;
    const int lane = threadIdx.x;
    const int l15 = lane & 15, lg = lane >> 4;
    const int qbase = qt * 64 + w * 32;

    const __hip_bfloat16* base = qkv + (size_t)b * TT * S3C;
    const int qo = h * 64, ko = 1024 + h * 64;
    const __hip_bfloat16* vt = Vt + (size_t)bh * 64 * TT;

    // Q B-fragments (pre-scaled by log2e/sqrt(C)): [m][half]
    bf16x8 aq[2][2];
#pragma unroll
    for (int m = 0; m < 2; ++m) {
        const __hip_bfloat16* qp = base + (size_t)(qbase + m * 16 + l15) * S3C + qo + lg * 8;
        aq[m][0] = *reinterpret_cast<const bf16x8*>(qp);
        aq[m][1] = *reinterpret_cast<const bf16x8*>(qp + 32);
    }

    float lrow[2] = {0.f, 0.f};  // in-lane partial row sums
    f32x4 acc[2][4] = {};        // [m][dg]: row=q(lg*4+j), col=d(dg*16+l15)

    const int nt = qt + 1;

    for (int kt = 0; kt < nt; ++kt) {
        const int kb = kt * 64;
        // ---- K A-frags direct from qkv: kf[cg][half]
        bf16x8 kf[4][2];
#pragma unroll
        for (int cg = 0; cg < 4; ++cg) {
            const __hip_bfloat16* kp = base + (size_t)(kb + cg * 16 + l15) * S3C + ko + lg * 8;
            kf[cg][0] = *reinterpret_cast<const bf16x8*>(kp);
            kf[cg][1] = *reinterpret_cast<const bf16x8*>(kp + 32);
        }
        // ---- QK^T (swapped): s[m][cg][j] = S[key=kb+16cg+4lg+j][q=qbase+16m+l15]
        f32x4 s[2][4];
        __builtin_amdgcn_s_setprio(1);
#pragma unroll
        for (int cg = 0; cg < 4; ++cg)
#pragma unroll
            for (int m = 0; m < 2; ++m) {
                f32x4 z = {0.f, 0.f, 0.f, 0.f};
                z = __builtin_amdgcn_mfma_f32_16x16x32_bf16(kf[cg][0], aq[m][0], z, 0, 0, 0);
                z = __builtin_amdgcn_mfma_f32_16x16x32_bf16(kf[cg][1], aq[m][1], z, 0, 0, 0);
                s[m][cg] = z;
            }
        __builtin_amdgcn_s_setprio(0);
        // ---- V B-frags direct from permuted Vt (latency hides under softmax)
        bf16x8 vb[2][4];
#pragma unroll
        for (int dg = 0; dg < 4; ++dg) {
            const __hip_bfloat16* vrow = vt + (size_t)(dg * 16 + l15) * TT + kb + lg * 8;
            vb[0][dg] = *reinterpret_cast<const bf16x8*>(vrow);
            vb[1][dg] = *reinterpret_cast<const bf16x8*>(vrow + 32);
        }
        // ---- max-free softmax: p = 2^s (masked -> 0); in-lane row-sum only
        float p[2][4][4];
        const bool needmask = (kb + 63 > qbase);
#pragma unroll
        for (int m = 0; m < 2; ++m) {
#pragma unroll
            for (int cg = 0; cg < 4; ++cg)
#pragma unroll
                for (int j = 0; j < 4; ++j) {
                    float e = fexp2(s[m][cg][j]);
                    if (needmask) {
                        int key = kb + cg * 16 + lg * 4 + j;
                        int qrow = qbase + m * 16 + l15;
                        e = (key > qrow) ? 0.f : e;
                    }
                    p[m][cg][j] = e;
                }
            float t0 = (p[m][0][0] + p[m][0][1]) + (p[m][0][2] + p[m][0][3]);
            float t1 = (p[m][1][0] + p[m][1][1]) + (p[m][1][2] + p[m][1][3]);
            float t2 = (p[m][2][0] + p[m][2][1]) + (p[m][2][2] + p[m][2][3]);
            float t3 = (p[m][3][0] + p[m][3][1]) + (p[m][3][2] + p[m][3][3]);
            lrow[m] += (t0 + t1) + (t2 + t3);
        }
        // ---- P A-frags: pure register pack (key-permutation baked into Vt)
        bf16x8 pa[2][2];
#pragma unroll
        for (int m = 0; m < 2; ++m)
#pragma unroll
            for (int ks = 0; ks < 2; ++ks) {
                bf16x8 t;
                t[0] = tobf(p[m][2 * ks][0]);
                t[1] = tobf(p[m][2 * ks][1]);
                t[2] = tobf(p[m][2 * ks][2]);
                t[3] = tobf(p[m][2 * ks][3]);
                t[4] = tobf(p[m][2 * ks + 1][0]);
                t[5] = tobf(p[m][2 * ks + 1][1]);
                t[6] = tobf(p[m][2 * ks + 1][2]);
                t[7] = tobf(p[m][2 * ks + 1][3]);
                pa[m][ks] = t;
            }
        // ---- PV
        __builtin_amdgcn_s_setprio(1);
#pragma unroll
        for (int ks = 0; ks < 2; ++ks)
#pragma unroll
            for (int dg = 0; dg < 4; ++dg)
#pragma unroll
                for (int m = 0; m < 2; ++m)
                    acc[m][dg] = __builtin_amdgcn_mfma_f32_16x16x32_bf16(pa[m][ks], vb[ks][dg],
                                                                         acc[m][dg], 0, 0, 0);
        __builtin_amdgcn_s_setprio(0);
    }

    // ---- epilogue: complete row sums across lg groups, redistribute, store
#pragma unroll
    for (int m = 0; m < 2; ++m) {
        float l = lrow[m];
        l += __shfl_xor(l, 16, 64);
        l += __shfl_xor(l, 32, 64);
        float inv = 1.f / l;  // valid at lane l15 = q (replicated over lg)
#pragma unroll
        for (int j = 0; j < 4; ++j) {
            float invj = __shfl(inv, lg * 4 + j, 64);
            int t = qbase + m * 16 + lg * 4 + j;
#pragma unroll
            for (int dg = 0; dg < 4; ++dg) {
                float o = acc[m][dg][j] * invj;
                y[((size_t)(b * TT + t)) * 1024 + h * 64 + dg * 16 + l15] = __float2bfloat16(o);
            }
        }
    }
}

// ---------------------------------------------------------------------------
extern "C" void kernel_launch(void* const* d_in, const int* in_sizes, int n_in,
                              void* d_out, int out_size, void* d_ws, size_t ws_size,
                              hipStream_t stream) {
    const float* x = (const float*)d_in[0];   // [4,2048,1024]
    const float* Wa = (const float*)d_in[1];  // [1024,3072]
    const float* Wp = (const float*)d_in[2];  // [1024,1024]
    float* out = (float*)d_out;               // [4,2048,1024] fp32

    __hip_bfloat16* ws = (__hip_bfloat16*)d_ws;
    __hip_bfloat16* x_bf = ws;                          // 8192*1024 (dead after GEMM1)
    __hip_bfloat16* WaT = x_bf + (size_t)8192 * 1024;   // 3072*1024 (W_attn^T)
    __hip_bfloat16* WpT = WaT + (size_t)3072 * 1024;    // 1024*1024 (W_proj^T)
    __hip_bfloat16* qkv = WpT + (size_t)1024 * 1024;    // 8192*3072
    __hip_bfloat16* ybf = qkv + (size_t)8192 * 3072;    // 8192*1024
    __hip_bfloat16* Vt = x_bf;                          // reuse: 64*64*2048 = 8192*1024

    // fused prep: x cvt + W_attn^T (Q cols scaled by log2e/sqrt(C)) + W_proj^T
    prep_k<<<8192 + 3072 + 1024, 256, 0, stream>>>(x, x_bf, Wa, WaT, Wp, WpT);
    // qkv = x @ W_attn   (M=8192, N=3072, K=1024)
    gemm_bt<true><<<dim3(24, 64), 256, 0, stream>>>(x_bf, WaT, qkv, nullptr, 8192, 3072, 1024);
    // V^T per head, key-permuted (x_bf is dead now; Vt aliases it)
    vtrans_k<<<dim3(64, 2, 64), 256, 0, stream>>>(qkv, Vt);
    // flash attention -> ybf (1-wave blocks, heavy-first, barrier-free)
    attn_k<<<dim3(64, 64), 64, 0, stream>>>(qkv, Vt, ybf);
    // out = y @ W_proj   (M=8192, N=1024, K=1024), fp32 out
    gemm_bt<false><<<dim3(8, 64), 256, 0, stream>>>(ybf, WpT, nullptr, out, 8192, 1024, 1024);
}

// Round 12
// 195.583 us; speedup vs baseline: 1.2678x; 1.2678x over previous
//
#include <hip/hip_runtime.h>
#include <hip/hip_bf16.h>

typedef __bf16 bf16x8 __attribute__((ext_vector_type(8)));
typedef float f32x4 __attribute__((ext_vector_type(4)));

static __device__ __forceinline__ __bf16 tobf(float x) {
    __hip_bfloat16 h = __float2bfloat16(x);
    __bf16 r;
    __builtin_memcpy(&r, &h, 2);
    return r;
}

// fast 2^x: single v_exp_f32 (no libm range-fixup code)
static __device__ __forceinline__ float fexp2(float x) {
    float r;
    asm("v_exp_f32 %0, %1" : "=v"(r) : "v"(x));
    return r;
}

// ---------------------------------------------------------------------------
// Fused prep: (a) x fp32 -> bf16 (vectorized), (b) W_attn^T with qscale
// folded into Q columns, (c) W_proj^T.  One launch instead of three.
// ---------------------------------------------------------------------------
__global__ __launch_bounds__(256) void prep_k(const float* __restrict__ x,
                                              __hip_bfloat16* __restrict__ x_bf,
                                              const float* __restrict__ Wa,
                                              __hip_bfloat16* __restrict__ WaT,
                                              const float* __restrict__ Wp,
                                              __hip_bfloat16* __restrict__ WpT) {
    __shared__ float tile[32][33];
    const int bid = blockIdx.x;
    const int tid = threadIdx.x;
    if (bid < 8192) {
        int i = bid * 256 + tid;
        float4 v = reinterpret_cast<const float4*>(x)[i];
        __hip_bfloat16 a = __float2bfloat16(v.x);
        __hip_bfloat16 b = __float2bfloat16(v.y);
        __hip_bfloat16 c = __float2bfloat16(v.z);
        __hip_bfloat16 d = __float2bfloat16(v.w);
        ushort4 o;
        o.x = *reinterpret_cast<unsigned short*>(&a);
        o.y = *reinterpret_cast<unsigned short*>(&b);
        o.z = *reinterpret_cast<unsigned short*>(&c);
        o.w = *reinterpret_cast<unsigned short*>(&d);
        reinterpret_cast<ushort4*>(x_bf)[i] = o;
        return;
    }
    const float* in;
    __hip_bfloat16* out;
    int bx, Cn, qrows;
    float qscale;
    int t;
    if (bid < 8192 + 3072) {
        t = bid - 8192;
        in = Wa; out = WaT; Cn = 3072; qrows = 1024;
        qscale = 0.045084223f;  // log2(e)/sqrt(1024)
        bx = t % 96;
    } else {
        t = bid - 11264;
        in = Wp; out = WpT; Cn = 1024; qrows = 0;
        qscale = 1.0f;
        bx = t % 32;
    }
    const int by = (bid < 11264) ? (t / 96) : (t / 32);
    const int R = 1024;
    const int c0 = bx * 32, r0 = by * 32;
    const int tx = tid & 31, ty = tid >> 5;  // 32 x 8
#pragma unroll
    for (int i = 0; i < 4; ++i)
        tile[ty + i * 8][tx] = in[(size_t)(r0 + ty + i * 8) * Cn + c0 + tx];
    __syncthreads();
#pragma unroll
    for (int i = 0; i < 4; ++i) {
        int orow = c0 + ty + i * 8;
        float v = tile[tx][ty + i * 8];
        if (orow < qrows) v *= qscale;
        out[(size_t)orow * R + r0 + tx] = __float2bfloat16(v);
    }
}

// ---------------------------------------------------------------------------
// V transpose + key-permute: qkv V-section [b][t][h*64+d] ->
// Vt[(b*16+h)*64+d][slot(t)], slot(r) = ((r&12)<<1)|(r&3)|((r>>4)<<2) within
// each 32-key block. Matches the register layout of swapped-QK^T P frags so
// the PV A-operand is a pure register pack.
// ---------------------------------------------------------------------------
__global__ __launch_bounds__(256) void vtrans_k(const __hip_bfloat16* __restrict__ qkv,
                                                __hip_bfloat16* __restrict__ Vt) {
    __shared__ __hip_bfloat16 tile[32][33];
    const int bh = blockIdx.z, b = bh >> 4, h = bh & 15;
    const int tt = blockIdx.x;  // 0..63 (t tile)
    const int dt = blockIdx.y;  // 0..1  (d tile)
    const int tx = threadIdx.x & 31, ty = threadIdx.x >> 5;  // 32 x 8
    const __hip_bfloat16* src = qkv + (size_t)b * 2048 * 3072 + 2048 + h * 64;
#pragma unroll
    for (int i = 0; i < 4; ++i)
        tile[ty + i * 8][tx] = src[(size_t)(tt * 32 + ty + i * 8) * 3072 + dt * 32 + tx];
    __syncthreads();
    const int slot = ((tx & 12) << 1) | (tx & 3) | ((tx >> 4) << 2);
    __hip_bfloat16* dst = Vt + ((size_t)bh * 64 + dt * 32) * 2048 + tt * 32;
#pragma unroll
    for (int i = 0; i < 4; ++i)
        dst[(size_t)(ty + i * 8) * 2048 + slot] = tile[tx][ty + i * 8];
}

// ---------------------------------------------------------------------------
// bf16 GEMM, C = A[M][K] * B, with B given transposed: Bt[N][K].
// m97 structure: 128x128 tile, BK=32, 4 waves each owning 64x64.
// XCD-aware tile swizzle (grid size divisible by 8).
// ---------------------------------------------------------------------------
template <bool OUT_BF16>
__global__ __launch_bounds__(256) void gemm_bt(const __hip_bfloat16* __restrict__ A,
                                               const __hip_bfloat16* __restrict__ Bt,
                                               __hip_bfloat16* __restrict__ Cb,
                                               float* __restrict__ Cf,
                                               int M, int N, int K) {
    __shared__ __attribute__((aligned(16))) __hip_bfloat16 As[128 * 32];
    __shared__ __attribute__((aligned(16))) __hip_bfloat16 Bs[128 * 32];
    const int tid = threadIdx.x;
    const int lane = tid & 63, wid = tid >> 6;
    const int l15 = lane & 15, lg = lane >> 4;
    const int wr = wid >> 1, wc = wid & 1;
    const int lin = blockIdx.y * gridDim.x + blockIdx.x;
    const int cpx = (gridDim.x * gridDim.y) >> 3;
    const int sw = (lin & 7) * cpx + (lin >> 3);
    const int bn = sw % gridDim.x, bm = sw / gridDim.x;
    const size_t arow0 = (size_t)bm * 128;
    const size_t brow0 = (size_t)bn * 128;

    f32x4 acc[4][4] = {};

    const int nk = K >> 5;
    for (int kt = 0; kt < nk; ++kt) {
        __syncthreads();
        {
            const int k0 = kt * 32;
#pragma unroll
            for (int p = 0; p < 2; ++p) {
                int idx = p * 256 + tid;
                int row = idx >> 2;
                int cc = (idx & 3) * 8;
                const __hip_bfloat16* ga = A + (arow0 + row) * (size_t)K + k0 + cc;
                const __hip_bfloat16* gb = Bt + (brow0 + row) * (size_t)K + k0 + cc;
                __builtin_amdgcn_global_load_lds(
                    (const __attribute__((address_space(1))) void*)ga,
                    (__attribute__((address_space(3))) void*)(&As[idx * 8]), 16, 0, 0);
                __builtin_amdgcn_global_load_lds(
                    (const __attribute__((address_space(1))) void*)gb,
                    (__attribute__((address_space(3))) void*)(&Bs[idx * 8]), 16, 0, 0);
            }
        }
        __syncthreads();
        bf16x8 af[4], bfr[4];
#pragma unroll
        for (int m = 0; m < 4; ++m)
            af[m] = *reinterpret_cast<const bf16x8*>(&As[(wr * 64 + m * 16 + l15) * 32 + lg * 8]);
#pragma unroll
        for (int n = 0; n < 4; ++n)
            bfr[n] = *reinterpret_cast<const bf16x8*>(&Bs[(wc * 64 + n * 16 + l15) * 32 + lg * 8]);
#pragma unroll
        for (int m = 0; m < 4; ++m)
#pragma unroll
            for (int n = 0; n < 4; ++n)
                acc[m][n] = __builtin_amdgcn_mfma_f32_16x16x32_bf16(af[m], bfr[n], acc[m][n], 0, 0, 0);
    }

#pragma unroll
    for (int m = 0; m < 4; ++m) {
#pragma unroll
        for (int n = 0; n < 4; ++n) {
#pragma unroll
            for (int j = 0; j < 4; ++j) {
                int row = bm * 128 + wr * 64 + m * 16 + lg * 4 + j;
                int col = bn * 128 + wc * 64 + n * 16 + l15;
                if (OUT_BF16)
                    Cb[(size_t)row * N + col] = __float2bfloat16(acc[m][n][j]);
                else
                    Cf[(size_t)row * N + col] = acc[m][n][j];
            }
        }
    }
}

// ---------------------------------------------------------------------------
// Flash attention (causal), swapped-QK^T, key-permuted V, MAX-FREE softmax,
// MFMA ROW-SUM, triangle-paired 2-pass blocks.
// Grid (bh=64, y=16); each 2-wave block runs qt = 31-y then qt = y (33
// tile-iterations per block, perfectly balanced).
// Row sums: instead of a VALU add-tree + epilogue shuffles, one extra
// mfma(pa, ones) per P-fragment accumulates D[q][.] = sum_k P[q][k] across
// tiles in a dedicated C operand, landing in exactly acc's row layout ->
// epilogue divide needs zero cross-lane ops, and normalization uses the
// same bf16-rounded P as PV (consistent).
// K staged double-buffered via global_load_lds (pre-swizzled source); V
// direct coalesced b128 from permuted Vt; P -> PV A-frag is a register pack;
// p = 2^s via single v_exp_f32 (log2e/sqrt(C) folded into W_attn's Q cols).
// ---------------------------------------------------------------------------
__global__ __launch_bounds__(128) void attn_k(const __hip_bfloat16* __restrict__ qkv,
                                              const __hip_bfloat16* __restrict__ Vt,
                                              __hip_bfloat16* __restrict__ y) {
    constexpr int TT = 2048;
    constexpr int S3C = 3072;
    const int bh = blockIdx.x, b = bh >> 4, h = bh & 15;
    const int tid = threadIdx.x;
    const int wid = tid >> 6, lane = tid & 63;
    const int l15 = lane & 15, lg = lane >> 4;

    __shared__ __attribute__((aligned(16))) char Ks[2][64 * 128];  // [key][d-chunk^swz]

    const __hip_bfloat16* base = qkv + (size_t)b * TT * S3C;
    const int qo = h * 64, ko = 1024 + h * 64;
    const __hip_bfloat16* vt = Vt + (size_t)bh * 64 * TT;

    // B-fragment of ones for the MFMA row-sum
    bf16x8 vones;
#pragma unroll
    for (int i = 0; i < 8; ++i) vones[i] = tobf(1.0f);

#define STAGE(BUF, KT)                                                                             \
    do {                                                                                           \
        const int kb_ = (KT) * 64;                                                                 \
        _Pragma("unroll") for (int p_ = 0; p_ < 4; ++p_) {                                         \
            int idx_ = p_ * 128 + tid;                                                             \
            int row_ = idx_ >> 3, c_ = idx_ & 7;                                                   \
            int col_ = 8 * (c_ ^ (row_ & 7));                                                      \
            __builtin_amdgcn_global_load_lds(                                                      \
                (const __attribute__((address_space(1))) void*)(base + (size_t)(kb_ + row_) * S3C + ko + col_), \
                (__attribute__((address_space(3))) void*)(&Ks[BUF][idx_ * 16]), 16, 0, 0);         \
        }                                                                                          \
    } while (0)

#pragma unroll 1
    for (int pass = 0; pass < 2; ++pass) {
        const int qt = pass == 0 ? (31 - (int)blockIdx.y) : (int)blockIdx.y;
        const int qbase = qt * 64 + wid * 32;
        const int nt = qt + 1;

        // Q B-fragments (pre-scaled by log2e/sqrt(C)): [m][half]
        bf16x8 aq[2][2];
#pragma unroll
        for (int m = 0; m < 2; ++m) {
            const __hip_bfloat16* qp = base + (size_t)(qbase + m * 16 + l15) * S3C + qo + lg * 8;
            aq[m][0] = *reinterpret_cast<const bf16x8*>(qp);
            aq[m][1] = *reinterpret_cast<const bf16x8*>(qp + 32);
        }

        f32x4 acc[2][4] = {};  // [m][dg]: row=q(lg*4+j), col=d(dg*16+l15)
        f32x4 lsum[2] = {};    // MFMA row-sums, same row layout as acc

        STAGE(0, 0);
        asm volatile("s_waitcnt vmcnt(0)" ::: "memory");
        __syncthreads();

        int cur = 0;
        for (int kt = 0; kt < nt; ++kt) {
            if (kt + 1 < nt) STAGE(cur ^ 1, kt + 1);
            const int kb = kt * 64;
            const char* Kb = &Ks[cur][0];
            const int sw = l15 & 7;
            // ---- QK^T (swapped): s[m][cg][j] = S[key=kb+16cg+4lg+j][q=qbase+16m+l15]
            f32x4 s[2][4];
            __builtin_amdgcn_s_setprio(1);
#pragma unroll
            for (int cg = 0; cg < 4; ++cg) {
                const char* krow = Kb + (cg * 16 + l15) * 128;
                bf16x8 k0 = *reinterpret_cast<const bf16x8*>(krow + 16 * (lg ^ sw));
                bf16x8 k1 = *reinterpret_cast<const bf16x8*>(krow + 16 * ((4 + lg) ^ sw));
#pragma unroll
                for (int m = 0; m < 2; ++m) {
                    f32x4 z = {0.f, 0.f, 0.f, 0.f};
                    z = __builtin_amdgcn_mfma_f32_16x16x32_bf16(k0, aq[m][0], z, 0, 0, 0);
                    z = __builtin_amdgcn_mfma_f32_16x16x32_bf16(k1, aq[m][1], z, 0, 0, 0);
                    s[m][cg] = z;
                }
            }
            __builtin_amdgcn_s_setprio(0);
            // ---- V B-frags direct from permuted Vt (issued early; consumed at PV)
            bf16x8 vb[2][4];
#pragma unroll
            for (int dg = 0; dg < 4; ++dg) {
                const __hip_bfloat16* vrow = vt + (size_t)(dg * 16 + l15) * TT + kb + lg * 8;
                vb[0][dg] = *reinterpret_cast<const bf16x8*>(vrow);
                vb[1][dg] = *reinterpret_cast<const bf16x8*>(vrow + 32);
            }
            // ---- max-free softmax: p = 2^s (masked -> 0); no row-sum VALU
            float p[2][4][4];
            const bool needmask = (kb + 63 > qbase);
#pragma unroll
            for (int m = 0; m < 2; ++m)
#pragma unroll
                for (int cg = 0; cg < 4; ++cg)
#pragma unroll
                    for (int j = 0; j < 4; ++j) {
                        float e = fexp2(s[m][cg][j]);
                        if (needmask) {
                            int key = kb + cg * 16 + lg * 4 + j;
                            int qrow = qbase + m * 16 + l15;
                            e = (key > qrow) ? 0.f : e;
                        }
                        p[m][cg][j] = e;
                    }
            // ---- P A-frags: pure register pack (key-permutation baked into Vt)
            bf16x8 pa[2][2];
#pragma unroll
            for (int m = 0; m < 2; ++m)
#pragma unroll
                for (int ks = 0; ks < 2; ++ks) {
                    bf16x8 t;
                    t[0] = tobf(p[m][2 * ks][0]);
                    t[1] = tobf(p[m][2 * ks][1]);
                    t[2] = tobf(p[m][2 * ks][2]);
                    t[3] = tobf(p[m][2 * ks][3]);
                    t[4] = tobf(p[m][2 * ks + 1][0]);
                    t[5] = tobf(p[m][2 * ks + 1][1]);
                    t[6] = tobf(p[m][2 * ks + 1][2]);
                    t[7] = tobf(p[m][2 * ks + 1][3]);
                    pa[m][ks] = t;
                }
            // ---- PV + MFMA row-sum
            __builtin_amdgcn_s_setprio(1);
#pragma unroll
            for (int ks = 0; ks < 2; ++ks) {
#pragma unroll
                for (int dg = 0; dg < 4; ++dg)
#pragma unroll
                    for (int m = 0; m < 2; ++m)
                        acc[m][dg] = __builtin_amdgcn_mfma_f32_16x16x32_bf16(pa[m][ks], vb[ks][dg],
                                                                             acc[m][dg], 0, 0, 0);
#pragma unroll
                for (int m = 0; m < 2; ++m)
                    lsum[m] = __builtin_amdgcn_mfma_f32_16x16x32_bf16(pa[m][ks], vones,
                                                                      lsum[m], 0, 0, 0);
            }
            __builtin_amdgcn_s_setprio(0);
            asm volatile("s_waitcnt vmcnt(0)" ::: "memory");
            __syncthreads();
            cur ^= 1;
        }

        // ---- epilogue: lsum already in acc row layout -> no cross-lane ops
#pragma unroll
        for (int m = 0; m < 2; ++m)
#pragma unroll
            for (int j = 0; j < 4; ++j) {
                float inv = 1.f / lsum[m][j];
                int t = qbase + m * 16 + lg * 4 + j;
#pragma unroll
                for (int dg = 0; dg < 4; ++dg) {
                    float o = acc[m][dg][j] * inv;
                    y[((size_t)(b * TT + t)) * 1024 + h * 64 + dg * 16 + l15] = __float2bfloat16(o);
                }
            }
    }
#undef STAGE
}

// ---------------------------------------------------------------------------
extern "C" void kernel_launch(void* const* d_in, const int* in_sizes, int n_in,
                              void* d_out, int out_size, void* d_ws, size_t ws_size,
                              hipStream_t stream) {
    const float* x = (const float*)d_in[0];   // [4,2048,1024]
    const float* Wa = (const float*)d_in[1];  // [1024,3072]
    const float* Wp = (const float*)d_in[2];  // [1024,1024]
    float* out = (float*)d_out;               // [4,2048,1024] fp32

    __hip_bfloat16* ws = (__hip_bfloat16*)d_ws;
    __hip_bfloat16* x_bf = ws;                          // 8192*1024 (dead after GEMM1)
    __hip_bfloat16* WaT = x_bf + (size_t)8192 * 1024;   // 3072*1024 (W_attn^T)
    __hip_bfloat16* WpT = WaT + (size_t)3072 * 1024;    // 1024*1024 (W_proj^T)
    __hip_bfloat16* qkv = WpT + (size_t)1024 * 1024;    // 8192*3072
    __hip_bfloat16* ybf = qkv + (size_t)8192 * 3072;    // 8192*1024
    __hip_bfloat16* Vt = x_bf;                          // reuse: 64*64*2048 = 8192*1024

    // fused prep: x cvt + W_attn^T (Q cols scaled by log2e/sqrt(C)) + W_proj^T
    prep_k<<<8192 + 3072 + 1024, 256, 0, stream>>>(x, x_bf, Wa, WaT, Wp, WpT);
    // qkv = x @ W_attn   (M=8192, N=3072, K=1024)
    gemm_bt<true><<<dim3(24, 64), 256, 0, stream>>>(x_bf, WaT, qkv, nullptr, 8192, 3072, 1024);
    // V^T per head, key-permuted (x_bf is dead now; Vt aliases it)
    vtrans_k<<<dim3(64, 2, 64), 256, 0, stream>>>(qkv, Vt);
    // flash attention -> ybf (triangle-paired 2-pass blocks, 64x16 grid)
    attn_k<<<dim3(64, 16), 128, 0, stream>>>(qkv, Vt, ybf);
    // out = y @ W_proj   (M=8192, N=1024, K=1024), fp32 out
    gemm_bt<false><<<dim3(8, 64), 256, 0, stream>>>(ybf, WpT, nullptr, out, 8192, 1024, 1024);
}